// Round 2
// baseline (261.630 us; speedup 1.0000x reference)
//
#include <hip/hip_runtime.h>

// MeanGraphSage: h = relu(concat(x @ Ws, mean_neighbors @ Wn) + bias)
// N=50000 nodes, E=800000 edges, D=64 in-feats, 128 out (64+64 concat).
//
// Strategy (round 2): replace the 51.2M-f32-atomic scatter (atomic-rate bound,
// 242 Gatomic/s, 225 MB write-through) with a counting-sort CSR build
// (2x 800K int atomics) + non-atomic wave-per-node register aggregation.

constexpr int N_NODES = 50000;
constexpr int N_EDGES = 800000;
constexpr int D = 64;
constexpr int UNITS = 128;

// ---------------- CSR-path kernels ----------------

__global__ __launch_bounds__(256) void edge_hist(const int* __restrict__ ei,
                                                 int* __restrict__ hist) {
    int e = blockIdx.x * blockDim.x + threadIdx.x;
    if (e < N_EDGES) atomicAdd(&hist[ei[e]], 1);
}

// Single-block exclusive scan over 50K degree counts -> offsets (+ a working
// copy "cursor" for the permute pass).
__global__ __launch_bounds__(1024) void scan_offsets(const int* __restrict__ hist,
                                                     int* __restrict__ offs,
                                                     int* __restrict__ cursor) {
    constexpr int CHUNK = (N_NODES + 1023) / 1024;  // 49
    __shared__ int sums[1024];
    const int t = threadIdx.x;
    int local[CHUNK];
    int run = 0;
    #pragma unroll
    for (int i = 0; i < CHUNK; ++i) {
        int idx = t * CHUNK + i;
        local[i] = run;
        run += (idx < N_NODES) ? hist[idx] : 0;
    }
    sums[t] = run;
    __syncthreads();
    // inclusive Hillis-Steele block scan
    for (int d2 = 1; d2 < 1024; d2 <<= 1) {
        int v = (t >= d2) ? sums[t - d2] : 0;
        __syncthreads();
        sums[t] += v;
        __syncthreads();
    }
    const int excl = sums[t] - run;  // exclusive prefix of this thread's chunk
    #pragma unroll
    for (int i = 0; i < CHUNK; ++i) {
        int idx = t * CHUNK + i;
        if (idx < N_NODES) {
            int o = excl + local[i];
            offs[idx]   = o;
            cursor[idx] = o;
        }
    }
}

// Permute edges into row-sorted order: (col, w) pairs.
__global__ __launch_bounds__(256) void edge_permute(const int* __restrict__ ei,
                                                    const float* __restrict__ ew,
                                                    int* __restrict__ cursor,
                                                    int* __restrict__ scol,
                                                    float* __restrict__ sw) {
    int e = blockIdx.x * blockDim.x + threadIdx.x;
    if (e < N_EDGES) {
        int row = ei[e];
        int pos = atomicAdd(&cursor[row], 1);
        scol[pos] = ei[N_EDGES + e];
        sw[pos]   = ew[e];
    }
}

// Wave-per-node: lane d accumulates feature d over the node's edge list in a
// register; one coalesced 256B gather per edge; single non-atomic write of the
// mean into the neighbor half of out. ends[] == cursor after permute
// (= offs[n] + deg[n]).
__global__ __launch_bounds__(256) void sage_aggregate(const float* __restrict__ x,
                                                      const int* __restrict__ offs,
                                                      const int* __restrict__ ends,
                                                      const int* __restrict__ scol,
                                                      const float* __restrict__ sw,
                                                      float* __restrict__ out) {
    const int lane = threadIdx.x & 63;
    const int n = blockIdx.x * 4 + (threadIdx.x >> 6);
    if (n >= N_NODES) return;
    const int s = offs[n];
    const int t = ends[n];
    float acc0 = 0.0f, acc1 = 0.0f;
    int e = s;
    for (; e + 1 < t; e += 2) {   // 2-deep ILP on the gather stream
        int   c0 = scol[e],  c1 = scol[e + 1];
        float w0 = sw[e],    w1 = sw[e + 1];
        acc0 = fmaf(x[c0 * D + lane], w0, acc0);
        acc1 = fmaf(x[c1 * D + lane], w1, acc1);
    }
    if (e < t) acc0 = fmaf(x[scol[e] * D + lane], sw[e], acc0);
    const float deg  = (float)(t - s);
    const float mean = (deg > 0.0f) ? (acc0 + acc1) / deg : 0.0f;
    out[n * UNITS + D + lane] = mean;
}

// ---------------- fallback (round-1) scatter ----------------

__global__ __launch_bounds__(256) void sage_scatter(const float* __restrict__ x,
                                                    const int* __restrict__ ei,
                                                    const float* __restrict__ ew,
                                                    float* __restrict__ out,
                                                    float* __restrict__ counts) {
    const int lane  = threadIdx.x & 63;
    const int wave  = blockIdx.x * (blockDim.x >> 6) + (threadIdx.x >> 6);
    const int nwave = gridDim.x * (blockDim.x >> 6);
    for (int e = wave; e < N_EDGES; e += nwave) {
        const int   row = ei[e];
        const int   col = ei[N_EDGES + e];
        const float w   = ew[e];
        atomicAdd(&out[row * UNITS + D + lane], x[col * D + lane] * w);
        if (lane == 0) atomicAdd(&counts[row], 1.0f);
    }
}

// ---------------- projection ----------------
// Each thread owns one output column j. counts==nullptr => neighbor half of
// out already holds the MEAN (CSR path); else it holds atomic SUMS to divide.
__global__ __launch_bounds__(256) void sage_project(const float* __restrict__ x,
                                                    const float* __restrict__ skern,
                                                    const float* __restrict__ nkern,
                                                    const float* __restrict__ bias,
                                                    const float* __restrict__ counts,
                                                    float* __restrict__ out) {
    const int tg = threadIdx.x >> 7;
    const int j  = threadIdx.x & 127;
    const int jj = j & (D - 1);
    const float* K = (j < D) ? skern : nkern;

    float kcol[D];
    #pragma unroll
    for (int k = 0; k < D; ++k) kcol[k] = K[k * D + jj];
    const float bj = bias[j];
    const int base = (j < D) ? 0 : D;

    __shared__ float feat[2][UNITS];

    for (int n = blockIdx.x * 2 + tg; n < N_NODES; n += gridDim.x * 2) {
        if (j < D) {
            feat[tg][j] = x[n * D + j];
        } else if (counts) {
            feat[tg][j] = out[n * UNITS + j] / fmaxf(counts[n], 1.0f);
        } else {
            feat[tg][j] = out[n * UNITS + j];
        }
        __syncthreads();
        float acc = 0.0f;
        #pragma unroll
        for (int k = 0; k < D; ++k) acc += feat[tg][base + k] * kcol[k];
        acc += bj;
        out[n * UNITS + j] = fmaxf(acc, 0.0f);
        __syncthreads();
    }
}

extern "C" void kernel_launch(void* const* d_in, const int* in_sizes, int n_in,
                              void* d_out, int out_size, void* d_ws, size_t ws_size,
                              hipStream_t stream) {
    const float* x     = (const float*)d_in[0];
    const int*   ei    = (const int*)  d_in[1];
    const float* ew    = (const float*)d_in[2];
    const float* skern = (const float*)d_in[3];
    const float* nkern = (const float*)d_in[4];
    const float* bias  = (const float*)d_in[5];
    float* out = (float*)d_out;

    // ws carve (256B-aligned regions)
    auto align256 = [](size_t v) { return (v + 255) & ~size_t(255); };
    const size_t szN = align256((size_t)N_NODES * sizeof(int));
    const size_t szE = align256((size_t)N_EDGES * sizeof(int));
    const size_t need = szN * 2 + szE * 2;

    if (ws_size >= need) {
        char* w = (char*)d_ws;
        int*   hist = (int*)w;                    // histogram, then cursor/ends
        int*   offs = (int*)(w + szN);
        int*   scol = (int*)(w + 2 * szN);
        float* sw   = (float*)(w + 2 * szN + szE);

        hipMemsetAsync(hist, 0, (size_t)N_NODES * sizeof(int), stream);
        edge_hist   <<<(N_EDGES + 255) / 256, 256, 0, stream>>>(ei, hist);
        scan_offsets<<<1, 1024, 0, stream>>>(hist, offs, hist /*cursor*/);
        edge_permute<<<(N_EDGES + 255) / 256, 256, 0, stream>>>(ei, ew, hist, scol, sw);
        sage_aggregate<<<(N_NODES + 3) / 4, 256, 0, stream>>>(x, offs, hist /*ends*/, scol, sw, out);
        sage_project<<<2048, 256, 0, stream>>>(x, skern, nkern, bias, nullptr, out);
    } else {
        // fallback: round-1 atomic path
        float* counts = (float*)d_ws;
        hipMemsetAsync(d_out, 0, (size_t)out_size * sizeof(float), stream);
        hipMemsetAsync(d_ws, 0, (size_t)N_NODES * sizeof(float), stream);
        sage_scatter<<<2048, 256, 0, stream>>>(x, ei, ew, out, counts);
        sage_project<<<2048, 256, 0, stream>>>(x, skern, nkern, bias, counts, out);
    }
}

// Round 3
// 172.070 us; speedup vs baseline: 1.5205x; 1.5205x over previous
//
#include <hip/hip_runtime.h>

// MeanGraphSage: h = relu(concat(x @ Ws, mean_neighbors @ Wn) + bias)
// N=50000 nodes, E=800000 edges, D=64 in-feats, 128 out (64+64 concat).
//
// Round 3: round-2's single-block scan was 82us (1 CU, latency-bound).
// Replace with 3-phase multi-block scan; pack permuted edges as uint64;
// 4-deep ILP in the gather loop.

constexpr int N_NODES = 50000;
constexpr int N_EDGES = 800000;
constexpr int D = 64;
constexpr int UNITS = 128;
constexpr int SCAN_BLK  = 256;
constexpr int SCAN_NBLK = (N_NODES + SCAN_BLK - 1) / SCAN_BLK;  // 196

// ---------------- CSR build ----------------

__global__ __launch_bounds__(256) void edge_hist(const int* __restrict__ ei,
                                                 int* __restrict__ hist) {
    int e = blockIdx.x * blockDim.x + threadIdx.x;
    if (e < N_EDGES) atomicAdd(&hist[ei[e]], 1);
}

// Phase A: per-block sums of 256-element chunks.
__global__ __launch_bounds__(SCAN_BLK) void scan_partial(const int* __restrict__ hist,
                                                         int* __restrict__ partials) {
    __shared__ int s[SCAN_BLK];
    const int t = threadIdx.x;
    const int idx = blockIdx.x * SCAN_BLK + t;
    s[t] = (idx < N_NODES) ? hist[idx] : 0;
    __syncthreads();
    for (int off = SCAN_BLK / 2; off > 0; off >>= 1) {
        if (t < off) s[t] += s[t + off];
        __syncthreads();
    }
    if (t == 0) partials[blockIdx.x] = s[0];
}

// Phase B: one small block scans the 196 partials -> exclusive bases.
__global__ __launch_bounds__(SCAN_BLK) void scan_tops(const int* __restrict__ partials,
                                                      int* __restrict__ bases) {
    __shared__ int s[SCAN_BLK];
    const int t = threadIdx.x;
    const int v = (t < SCAN_NBLK) ? partials[t] : 0;
    s[t] = v;
    __syncthreads();
    for (int d2 = 1; d2 < SCAN_BLK; d2 <<= 1) {
        int u = (t >= d2) ? s[t - d2] : 0;
        __syncthreads();
        s[t] += u;
        __syncthreads();
    }
    if (t < SCAN_NBLK) bases[t] = s[t] - v;  // exclusive
}

// Phase C: block-local exclusive scan + base -> offs & cursor.
__global__ __launch_bounds__(SCAN_BLK) void scan_apply(const int* __restrict__ hist,
                                                       const int* __restrict__ bases,
                                                       int* __restrict__ offs,
                                                       int* __restrict__ cursor) {
    __shared__ int s[SCAN_BLK];
    const int t = threadIdx.x;
    const int idx = blockIdx.x * SCAN_BLK + t;
    const int v = (idx < N_NODES) ? hist[idx] : 0;
    s[t] = v;
    __syncthreads();
    for (int d2 = 1; d2 < SCAN_BLK; d2 <<= 1) {
        int u = (t >= d2) ? s[t - d2] : 0;
        __syncthreads();
        s[t] += u;
        __syncthreads();
    }
    if (idx < N_NODES) {
        int o = bases[blockIdx.x] + s[t] - v;
        offs[idx]   = o;
        cursor[idx] = o;
    }
}

// Permute edges into row-sorted order; (col,w) packed into one 8B word so the
// random scatter is a single store.
__global__ __launch_bounds__(256) void edge_permute(const int* __restrict__ ei,
                                                    const float* __restrict__ ew,
                                                    int* __restrict__ cursor,
                                                    unsigned long long* __restrict__ packed) {
    int e = blockIdx.x * blockDim.x + threadIdx.x;
    if (e < N_EDGES) {
        const int   row = ei[e];
        const int   col = ei[N_EDGES + e];
        const float w   = ew[e];
        const int   pos = atomicAdd(&cursor[row], 1);
        packed[pos] = ((unsigned long long)(unsigned)col << 32) | (unsigned)__float_as_uint(w);
    }
}

// Wave-per-node aggregation: lane d owns feature d; 4-deep ILP on the gather
// stream; one non-atomic write of the mean into the neighbor half of out.
__global__ __launch_bounds__(256) void sage_aggregate(const float* __restrict__ x,
                                                      const int* __restrict__ offs,
                                                      const int* __restrict__ ends,
                                                      const unsigned long long* __restrict__ packed,
                                                      float* __restrict__ out) {
    const int lane = threadIdx.x & 63;
    const int n = blockIdx.x * 4 + (threadIdx.x >> 6);
    if (n >= N_NODES) return;
    const int s = offs[n];
    const int t = ends[n];
    float a0 = 0.f, a1 = 0.f, a2 = 0.f, a3 = 0.f;
    int e = s;
    for (; e + 3 < t; e += 4) {
        unsigned long long p0 = packed[e],     p1 = packed[e + 1];
        unsigned long long p2 = packed[e + 2], p3 = packed[e + 3];
        const int c0 = (int)(p0 >> 32), c1 = (int)(p1 >> 32);
        const int c2 = (int)(p2 >> 32), c3 = (int)(p3 >> 32);
        a0 = fmaf(x[c0 * D + lane], __uint_as_float((unsigned)p0), a0);
        a1 = fmaf(x[c1 * D + lane], __uint_as_float((unsigned)p1), a1);
        a2 = fmaf(x[c2 * D + lane], __uint_as_float((unsigned)p2), a2);
        a3 = fmaf(x[c3 * D + lane], __uint_as_float((unsigned)p3), a3);
    }
    for (; e < t; ++e) {
        unsigned long long p = packed[e];
        a0 = fmaf(x[(int)(p >> 32) * D + lane], __uint_as_float((unsigned)p), a0);
    }
    const float deg  = (float)(t - s);
    const float mean = (deg > 0.f) ? ((a0 + a1) + (a2 + a3)) / deg : 0.f;
    out[n * UNITS + D + lane] = mean;
}

// ---------------- fallback (round-1) scatter ----------------

__global__ __launch_bounds__(256) void sage_scatter(const float* __restrict__ x,
                                                    const int* __restrict__ ei,
                                                    const float* __restrict__ ew,
                                                    float* __restrict__ out,
                                                    float* __restrict__ counts) {
    const int lane  = threadIdx.x & 63;
    const int wave  = blockIdx.x * (blockDim.x >> 6) + (threadIdx.x >> 6);
    const int nwave = gridDim.x * (blockDim.x >> 6);
    for (int e = wave; e < N_EDGES; e += nwave) {
        atomicAdd(&out[ei[e] * UNITS + D + lane], x[ei[N_EDGES + e] * D + lane] * ew[e]);
        if (lane == 0) atomicAdd(&counts[ei[e]], 1.0f);
    }
}

// ---------------- projection ----------------
// counts==nullptr => neighbor half of out already holds the MEAN.
__global__ __launch_bounds__(256) void sage_project(const float* __restrict__ x,
                                                    const float* __restrict__ skern,
                                                    const float* __restrict__ nkern,
                                                    const float* __restrict__ bias,
                                                    const float* __restrict__ counts,
                                                    float* __restrict__ out) {
    const int tg = threadIdx.x >> 7;
    const int j  = threadIdx.x & 127;
    const int jj = j & (D - 1);
    const float* K = (j < D) ? skern : nkern;

    float kcol[D];
    #pragma unroll
    for (int k = 0; k < D; ++k) kcol[k] = K[k * D + jj];
    const float bj = bias[j];
    const int base = (j < D) ? 0 : D;

    __shared__ float feat[2][UNITS];

    for (int n = blockIdx.x * 2 + tg; n < N_NODES; n += gridDim.x * 2) {
        if (j < D) {
            feat[tg][j] = x[n * D + j];
        } else if (counts) {
            feat[tg][j] = out[n * UNITS + j] / fmaxf(counts[n], 1.0f);
        } else {
            feat[tg][j] = out[n * UNITS + j];
        }
        __syncthreads();
        float acc = 0.0f;
        #pragma unroll
        for (int k = 0; k < D; ++k) acc += feat[tg][base + k] * kcol[k];
        acc += bj;
        out[n * UNITS + j] = fmaxf(acc, 0.0f);
        __syncthreads();
    }
}

extern "C" void kernel_launch(void* const* d_in, const int* in_sizes, int n_in,
                              void* d_out, int out_size, void* d_ws, size_t ws_size,
                              hipStream_t stream) {
    const float* x     = (const float*)d_in[0];
    const int*   ei    = (const int*)  d_in[1];
    const float* ew    = (const float*)d_in[2];
    const float* skern = (const float*)d_in[3];
    const float* nkern = (const float*)d_in[4];
    const float* bias  = (const float*)d_in[5];
    float* out = (float*)d_out;

    auto align256 = [](size_t v) { return (v + 255) & ~size_t(255); };
    const size_t szN  = align256((size_t)N_NODES * sizeof(int));
    const size_t szP  = align256((size_t)SCAN_BLK * sizeof(int));
    const size_t szE8 = align256((size_t)N_EDGES * sizeof(unsigned long long));
    const size_t need = 2 * szN + 2 * szP + szE8;

    if (ws_size >= need) {
        char* w = (char*)d_ws;
        int* hist = (int*)w;                       // histogram -> cursor -> ends
        int* offs = (int*)(w + szN);
        int* partials = (int*)(w + 2 * szN);
        int* bases    = (int*)(w + 2 * szN + szP);
        unsigned long long* packed = (unsigned long long*)(w + 2 * szN + 2 * szP);

        hipMemsetAsync(hist, 0, (size_t)N_NODES * sizeof(int), stream);
        edge_hist   <<<(N_EDGES + 255) / 256, 256, 0, stream>>>(ei, hist);
        scan_partial<<<SCAN_NBLK, SCAN_BLK, 0, stream>>>(hist, partials);
        scan_tops   <<<1, SCAN_BLK, 0, stream>>>(partials, bases);
        scan_apply  <<<SCAN_NBLK, SCAN_BLK, 0, stream>>>(hist, bases, offs, hist /*cursor*/);
        edge_permute<<<(N_EDGES + 255) / 256, 256, 0, stream>>>(ei, ew, hist, packed);
        sage_aggregate<<<(N_NODES + 3) / 4, 256, 0, stream>>>(x, offs, hist /*ends*/, packed, out);
        sage_project<<<2048, 256, 0, stream>>>(x, skern, nkern, bias, nullptr, out);
    } else {
        float* counts = (float*)d_ws;
        hipMemsetAsync(d_out, 0, (size_t)out_size * sizeof(float), stream);
        hipMemsetAsync(d_ws, 0, (size_t)N_NODES * sizeof(float), stream);
        sage_scatter<<<2048, 256, 0, stream>>>(x, ei, ew, out, counts);
        sage_project<<<2048, 256, 0, stream>>>(x, skern, nkern, bias, counts, out);
    }
}

// Round 4
// 169.552 us; speedup vs baseline: 1.5431x; 1.0148x over previous
//
#include <hip/hip_runtime.h>

// MeanGraphSage: h = relu(concat(x @ Ws, mean_neighbors @ Wn) + bias)
// N=50000 nodes, E=800000 edges, D=64 in-feats, 128 out (64+64 concat).
//
// Round 4: edge_permute was write-amplification bound (52 MB HBM writes for a
// 6.4 MB logical scatter; every 8B random store dirtied a 64B line split
// across 8 XCD L2s). Fix: XCD-affine region filtering -- packed[] split into
// 8 x 100K-edge regions (800 KB, L2-resident); blocks with blockIdx&7==q
// process only edges destined for region q, so each line is written by one
// XCD and written back once. Aggregate gets the same affinity so its packed
// reads are L2 hits.

constexpr int N_NODES = 50000;
constexpr int N_EDGES = 800000;
constexpr int D = 64;
constexpr int UNITS = 128;
constexpr int SCAN_BLK  = 256;
constexpr int SCAN_NBLK = (N_NODES + SCAN_BLK - 1) / SCAN_BLK;  // 196
constexpr int NXCD = 8;
constexpr int REG_EDGES = N_EDGES / NXCD;  // 100000 (exact)

// ---------------- CSR build ----------------

__global__ __launch_bounds__(256) void edge_hist(const int* __restrict__ ei,
                                                 int* __restrict__ hist) {
    int e = blockIdx.x * blockDim.x + threadIdx.x;
    if (e < N_EDGES) atomicAdd(&hist[ei[e]], 1);
}

__global__ __launch_bounds__(SCAN_BLK) void scan_partial(const int* __restrict__ hist,
                                                         int* __restrict__ partials) {
    __shared__ int s[SCAN_BLK];
    const int t = threadIdx.x;
    const int idx = blockIdx.x * SCAN_BLK + t;
    s[t] = (idx < N_NODES) ? hist[idx] : 0;
    __syncthreads();
    for (int off = SCAN_BLK / 2; off > 0; off >>= 1) {
        if (t < off) s[t] += s[t + off];
        __syncthreads();
    }
    if (t == 0) partials[blockIdx.x] = s[0];
}

__global__ __launch_bounds__(SCAN_BLK) void scan_tops(const int* __restrict__ partials,
                                                      int* __restrict__ bases) {
    __shared__ int s[SCAN_BLK];
    const int t = threadIdx.x;
    const int v = (t < SCAN_NBLK) ? partials[t] : 0;
    s[t] = v;
    __syncthreads();
    for (int d2 = 1; d2 < SCAN_BLK; d2 <<= 1) {
        int u = (t >= d2) ? s[t - d2] : 0;
        __syncthreads();
        s[t] += u;
        __syncthreads();
    }
    if (t < SCAN_NBLK) bases[t] = s[t] - v;  // exclusive
}

__global__ __launch_bounds__(SCAN_BLK) void scan_apply(const int* __restrict__ hist,
                                                       const int* __restrict__ bases,
                                                       int* __restrict__ offs,
                                                       int* __restrict__ cursor) {
    __shared__ int s[SCAN_BLK];
    const int t = threadIdx.x;
    const int idx = blockIdx.x * SCAN_BLK + t;
    const int v = (idx < N_NODES) ? hist[idx] : 0;
    s[t] = v;
    __syncthreads();
    for (int d2 = 1; d2 < SCAN_BLK; d2 <<= 1) {
        int u = (t >= d2) ? s[t - d2] : 0;
        __syncthreads();
        s[t] += u;
        __syncthreads();
    }
    if (idx < N_NODES) {
        int o = bases[blockIdx.x] + s[t] - v;
        offs[idx]   = o;
        cursor[idx] = o;
    }
}

// XCD-affine permute: block's XCD q = blockIdx&7; scans all edges (row array
// is L3-resident after first group touches it), processes only edges whose
// destination position lies in region q. Writes stay L2-resident until full.
__global__ __launch_bounds__(256) void edge_permute(const int* __restrict__ ei,
                                                    const float* __restrict__ ew,
                                                    const int* __restrict__ offs,
                                                    int* __restrict__ cursor,
                                                    unsigned long long* __restrict__ packed) {
    const int xcd  = blockIdx.x & (NXCD - 1);
    const int tid  = (blockIdx.x >> 3) * blockDim.x + threadIdx.x;
    const int strd = (gridDim.x >> 3) * blockDim.x;
    const int lo = xcd * REG_EDGES;
    const int hi = lo + REG_EDGES;
    for (int e = tid; e < N_EDGES; e += strd) {
        const int row = ei[e];
        const int o   = offs[row];
        if (o < lo || o >= hi) continue;   // another XCD's region
        const int   col = ei[N_EDGES + e];
        const float w   = ew[e];
        const int   pos = atomicAdd(&cursor[row], 1);
        packed[pos] = ((unsigned long long)(unsigned)col << 32) | (unsigned)__float_as_uint(w);
    }
}

__device__ __forceinline__ int lower_bound_offs(const int* __restrict__ offs, int val) {
    int lo = 0, hi = N_NODES;
    while (lo < hi) {
        int mid = (lo + hi) >> 1;
        if (offs[mid] < val) lo = mid + 1; else hi = mid;
    }
    return lo;
}

// XCD-affine wave-per-node aggregation: each XCD handles the node range whose
// packed edges live in its region (L2 hits). Lane d owns feature d; 4-deep
// gather ILP; single non-atomic mean write.
__global__ __launch_bounds__(256) void sage_aggregate(const float* __restrict__ x,
                                                      const int* __restrict__ offs,
                                                      const int* __restrict__ ends,
                                                      const unsigned long long* __restrict__ packed,
                                                      float* __restrict__ out) {
    const int xcd   = blockIdx.x & (NXCD - 1);
    const int lane  = threadIdx.x & 63;
    const int wgrp  = (blockIdx.x >> 3) * (blockDim.x >> 6) + (threadIdx.x >> 6);
    const int nwgrp = (gridDim.x >> 3) * (blockDim.x >> 6);
    const int lo = xcd * REG_EDGES;
    const int n0 = lower_bound_offs(offs, lo);
    const int n1 = (xcd == NXCD - 1) ? N_NODES : lower_bound_offs(offs, lo + REG_EDGES);
    for (int n = n0 + wgrp; n < n1; n += nwgrp) {
        const int s = offs[n];
        const int t = ends[n];
        float a0 = 0.f, a1 = 0.f, a2 = 0.f, a3 = 0.f;
        int e = s;
        for (; e + 3 < t; e += 4) {
            unsigned long long p0 = packed[e],     p1 = packed[e + 1];
            unsigned long long p2 = packed[e + 2], p3 = packed[e + 3];
            a0 = fmaf(x[(int)(p0 >> 32) * D + lane], __uint_as_float((unsigned)p0), a0);
            a1 = fmaf(x[(int)(p1 >> 32) * D + lane], __uint_as_float((unsigned)p1), a1);
            a2 = fmaf(x[(int)(p2 >> 32) * D + lane], __uint_as_float((unsigned)p2), a2);
            a3 = fmaf(x[(int)(p3 >> 32) * D + lane], __uint_as_float((unsigned)p3), a3);
        }
        for (; e < t; ++e) {
            unsigned long long p = packed[e];
            a0 = fmaf(x[(int)(p >> 32) * D + lane], __uint_as_float((unsigned)p), a0);
        }
        const float deg  = (float)(t - s);
        const float mean = (deg > 0.f) ? ((a0 + a1) + (a2 + a3)) / deg : 0.f;
        out[n * UNITS + D + lane] = mean;
    }
}

// ---------------- fallback (round-1) scatter ----------------

__global__ __launch_bounds__(256) void sage_scatter(const float* __restrict__ x,
                                                    const int* __restrict__ ei,
                                                    const float* __restrict__ ew,
                                                    float* __restrict__ out,
                                                    float* __restrict__ counts) {
    const int lane  = threadIdx.x & 63;
    const int wave  = blockIdx.x * (blockDim.x >> 6) + (threadIdx.x >> 6);
    const int nwave = gridDim.x * (blockDim.x >> 6);
    for (int e = wave; e < N_EDGES; e += nwave) {
        atomicAdd(&out[ei[e] * UNITS + D + lane], x[ei[N_EDGES + e] * D + lane] * ew[e]);
        if (lane == 0) atomicAdd(&counts[ei[e]], 1.0f);
    }
}

// ---------------- projection ----------------
// counts==nullptr => neighbor half of out already holds the MEAN.
__global__ __launch_bounds__(256) void sage_project(const float* __restrict__ x,
                                                    const float* __restrict__ skern,
                                                    const float* __restrict__ nkern,
                                                    const float* __restrict__ bias,
                                                    const float* __restrict__ counts,
                                                    float* __restrict__ out) {
    const int tg = threadIdx.x >> 7;
    const int j  = threadIdx.x & 127;
    const int jj = j & (D - 1);
    const float* K = (j < D) ? skern : nkern;

    float kcol[D];
    #pragma unroll
    for (int k = 0; k < D; ++k) kcol[k] = K[k * D + jj];
    const float bj = bias[j];
    const int base = (j < D) ? 0 : D;

    __shared__ float feat[2][UNITS];

    for (int n = blockIdx.x * 2 + tg; n < N_NODES; n += gridDim.x * 2) {
        if (j < D) {
            feat[tg][j] = x[n * D + j];
        } else if (counts) {
            feat[tg][j] = out[n * UNITS + j] / fmaxf(counts[n], 1.0f);
        } else {
            feat[tg][j] = out[n * UNITS + j];
        }
        __syncthreads();
        float acc = 0.0f;
        #pragma unroll
        for (int k = 0; k < D; ++k) acc += feat[tg][base + k] * kcol[k];
        acc += bj;
        out[n * UNITS + j] = fmaxf(acc, 0.0f);
        __syncthreads();
    }
}

extern "C" void kernel_launch(void* const* d_in, const int* in_sizes, int n_in,
                              void* d_out, int out_size, void* d_ws, size_t ws_size,
                              hipStream_t stream) {
    const float* x     = (const float*)d_in[0];
    const int*   ei    = (const int*)  d_in[1];
    const float* ew    = (const float*)d_in[2];
    const float* skern = (const float*)d_in[3];
    const float* nkern = (const float*)d_in[4];
    const float* bias  = (const float*)d_in[5];
    float* out = (float*)d_out;

    auto align256 = [](size_t v) { return (v + 255) & ~size_t(255); };
    const size_t szN  = align256((size_t)N_NODES * sizeof(int));
    const size_t szP  = align256((size_t)SCAN_BLK * sizeof(int));
    const size_t szE8 = align256((size_t)N_EDGES * sizeof(unsigned long long));
    const size_t need = 2 * szN + 2 * szP + szE8;

    if (ws_size >= need) {
        char* w = (char*)d_ws;
        int* hist = (int*)w;                       // histogram -> cursor -> ends
        int* offs = (int*)(w + szN);
        int* partials = (int*)(w + 2 * szN);
        int* bases    = (int*)(w + 2 * szN + szP);
        unsigned long long* packed = (unsigned long long*)(w + 2 * szN + 2 * szP);

        hipMemsetAsync(hist, 0, (size_t)N_NODES * sizeof(int), stream);
        edge_hist   <<<(N_EDGES + 255) / 256, 256, 0, stream>>>(ei, hist);
        scan_partial<<<SCAN_NBLK, SCAN_BLK, 0, stream>>>(hist, partials);
        scan_tops   <<<1, SCAN_BLK, 0, stream>>>(partials, bases);
        scan_apply  <<<SCAN_NBLK, SCAN_BLK, 0, stream>>>(hist, bases, offs, hist /*cursor*/);
        edge_permute<<<2048, 256, 0, stream>>>(ei, ew, offs, hist /*cursor*/, packed);
        sage_aggregate<<<2048, 256, 0, stream>>>(x, offs, hist /*ends*/, packed, out);
        sage_project<<<2048, 256, 0, stream>>>(x, skern, nkern, bias, nullptr, out);
    } else {
        float* counts = (float*)d_ws;
        hipMemsetAsync(d_out, 0, (size_t)out_size * sizeof(float), stream);
        hipMemsetAsync(d_ws, 0, (size_t)N_NODES * sizeof(float), stream);
        sage_scatter<<<2048, 256, 0, stream>>>(x, ei, ew, out, counts);
        sage_project<<<2048, 256, 0, stream>>>(x, skern, nkern, bias, counts, out);
    }
}